// Round 2
// baseline (296.855 us; speedup 1.0000x reference)
//
#include <hip/hip_runtime.h>

#define T_SEQ 2048
#define DM 1024
#define NH 16
#define DKH 64
#define NB 2
#define M_ROWS (NB * T_SEQ)  // 4096
#define QSCALE 0.18033688011112042f  // 0.125 * log2(e): exp2 domain

using bf16x8 = __attribute__((ext_vector_type(8))) __bf16;
using f32x4  = __attribute__((ext_vector_type(4))) float;
using halfx4 = __attribute__((ext_vector_type(4))) __fp16;
using halfx8 = __attribute__((ext_vector_type(8))) __fp16;
using halfx2 = __attribute__((ext_vector_type(2))) __fp16;
using uintx4 = __attribute__((ext_vector_type(4))) unsigned;

__device__ __forceinline__ short f2bf(float f) {
  unsigned u = __builtin_bit_cast(unsigned, f);
  u += 0x7fffu + ((u >> 16) & 1u);
  return (short)(u >> 16);
}

#if defined(__has_builtin) && __has_builtin(__builtin_amdgcn_cvt_pk_bf16_f32)
using bf16x2 = __attribute__((ext_vector_type(2))) __bf16;
__device__ __forceinline__ short2 pk2(float a, float b) {
  bf16x2 r = __builtin_amdgcn_cvt_pk_bf16_f32(a, b);
  return __builtin_bit_cast(short2, r);
}
#else
__device__ __forceinline__ short2 pk2(float a, float b) {
  short2 r; r.x = f2bf(a); r.y = f2bf(b); return r;
}
#endif

__device__ __forceinline__ short2 pkh(float a, float b) {  // f32x2 -> f16x2 (RTZ)
  halfx2 r = __builtin_amdgcn_cvt_pkrtz(a, b);
  return __builtin_bit_cast(short2, r);
}

#if defined(__has_builtin) && __has_builtin(__builtin_amdgcn_exp2f)
__device__ __forceinline__ float fexp2(float x) { return __builtin_amdgcn_exp2f(x); }
#else
__device__ __forceinline__ float fexp2(float x) { return exp2f(x); }
#endif

// gfx950 cross-lane row swaps (for P-fragment redistribution in PV).
// swap32: a' = [a.lo32, b.lo32], b' = [a.hi32, b.hi32]
// swap16: a' = [a.r0, b.r0, a.r2, b.r2], b' = [a.r1, b.r1, a.r3, b.r3]
#if defined(__has_builtin) && __has_builtin(__builtin_amdgcn_permlane32_swap) && \
    __has_builtin(__builtin_amdgcn_permlane16_swap)
using uintx2 = __attribute__((ext_vector_type(2))) unsigned;
__device__ __forceinline__ void swap32(unsigned& a, unsigned& b) {
  uintx2 r = __builtin_amdgcn_permlane32_swap(a, b, false, false);
  a = r.x; b = r.y;
}
__device__ __forceinline__ void swap16(unsigned& a, unsigned& b) {
  uintx2 r = __builtin_amdgcn_permlane16_swap(a, b, false, false);
  a = r.x; b = r.y;
}
#else
__device__ __forceinline__ void swap32(unsigned& a, unsigned& b) {
  asm volatile("v_permlane32_swap_b32 %0, %1" : "+v"(a), "+v"(b));
}
__device__ __forceinline__ void swap16(unsigned& a, unsigned& b) {
  asm volatile("v_permlane16_swap_b32 %0, %1" : "+v"(a), "+v"(b));
}
#endif

#define GLD16(g, l)                                                            \
  __builtin_amdgcn_global_load_lds(                                            \
      (const __attribute__((address_space(1))) void*)(g),                      \
      (__attribute__((address_space(3))) void*)(l), 16, 0, 0)

// ---------- prep: fp32 -> bf16 of q,k,v; mask -> additive float ----------
__global__ __launch_bounds__(256) void prep_x(
    const float* __restrict__ q, const float* __restrict__ k,
    const float* __restrict__ v, const int* __restrict__ mask,
    short* __restrict__ dst, float* __restrict__ mf) {
  const float* s = blockIdx.z == 0 ? q : (blockIdx.z == 1 ? k : v);
  short* d = dst + (size_t)blockIdx.z * (M_ROWS * DM);
  const int n4 = M_ROWS * DM / 4;
  for (int i = blockIdx.x * 256 + threadIdx.x; i < n4; i += gridDim.x * 256) {
    float4 f = *(const float4*)(s + i * 4);
    short2 a = pk2(f.x, f.y), b = pk2(f.z, f.w);
    short4 o = {a.x, a.y, b.x, b.y};
    *(short4*)(d + i * 4) = o;
  }
  if (blockIdx.z == 0 && blockIdx.x < 4) {
    int i = (blockIdx.x * 256 + threadIdx.x) * 4;
    int4 m = *(const int4*)(mask + i);
    float4 o = {m.x ? 0.f : -1e38f, m.y ? 0.f : -1e38f,
                m.z ? 0.f : -1e38f, m.w ? 0.f : -1e38f};
    *(float4*)(mf + i) = o;
  }
}

// ---------- prep: W [k][n] fp32 -> Wt [n][k] bf16 (4 matrices) ----------
__global__ __launch_bounds__(256) void prep_w(
    const float* __restrict__ w0, const float* __restrict__ w1,
    const float* __restrict__ w2, const float* __restrict__ w3,
    short* __restrict__ dst) {
  __shared__ short T[64][72];
  const float* W = blockIdx.z == 0 ? w0 : blockIdx.z == 1 ? w1
                   : blockIdx.z == 2 ? w2 : w3;
  short* D = dst + (size_t)blockIdx.z * (DM * DM);
  const int k0 = blockIdx.x * 64, n0 = blockIdx.y * 64;
  const int r = threadIdx.x >> 2, cs = (threadIdx.x & 3) * 16;
#pragma unroll
  for (int j = 0; j < 4; ++j) {
    float4 f = *(const float4*)(W + (size_t)(k0 + r) * DM + n0 + cs + j * 4);
    short2 a = pk2(f.x, f.y), b = pk2(f.z, f.w);
    short4 o = {a.x, a.y, b.x, b.y};
    *(short4*)&T[r][cs + j * 4] = o;
  }
  __syncthreads();
  short tmp[16];
#pragma unroll
  for (int i = 0; i < 16; ++i) tmp[i] = T[cs + i][r];
  *(int4*)(D + (size_t)(n0 + r) * DM + k0 + cs) = *(const int4*)&tmp[0];
  *(int4*)(D + (size_t)(n0 + r) * DM + k0 + cs + 8) = *(const int4*)&tmp[8];
}

// ---------- QKV GEMM (r8 512-thr form, proven): Y = A @ Bt^T + bias ----------
// z<2: headsplit bf16 [b][h][t][dk] scalar coalesced (z==0 folds QSCALE);
// z==2: V^T [b][h][dk][t] in F16 (short4 over 4 consecutive t).
__global__ __launch_bounds__(512) void gemm_qkv(
    const short* __restrict__ A_, const short* __restrict__ Bt_,
    const float* __restrict__ b0, const float* __restrict__ b1,
    const float* __restrict__ b2, short* __restrict__ Y) {
  __shared__ short As[2][4096];
  __shared__ short Bs[2][4096];
  const int z = blockIdx.z;
  const short* A = A_ + (size_t)z * (M_ROWS * DM);
  const short* Bt = Bt_ + (size_t)z * (DM * DM);
  short* Yz = Y + (size_t)z * ((size_t)M_ROWS * DM);
  const float* bias = z == 0 ? b0 : (z == 1 ? b1 : b2);
  const int m0 = blockIdx.x * 128, n0 = blockIdx.y * 128;
  const int tid = threadIdx.x, w = tid >> 6, lane = tid & 63;
  const int quad = lane >> 4, lm = lane & 15, wa = w & 1, wb = w >> 1;

  const short* Ag = A + (size_t)(m0 + w * 16 + lm) * DM + quad * 8;
  const short* Bg = Bt + (size_t)(n0 + w * 16 + lm) * DM + quad * 8;

  f32x4 acc[4][2];
#pragma unroll
  for (int i = 0; i < 4; ++i)
#pragma unroll
    for (int j = 0; j < 2; ++j) acc[i][j] = (f32x4){0.f, 0.f, 0.f, 0.f};

  GLD16(Ag, &As[0][w * 512]);
  GLD16(Bg, &Bs[0][w * 512]);

  for (int kt = 0; kt < DM / 32; ++kt) {
    const int cb = kt & 1;
    __syncthreads();
    if (kt + 1 < DM / 32) {
      GLD16(Ag + (kt + 1) * 32, &As[cb ^ 1][w * 512]);
      GLD16(Bg + (kt + 1) * 32, &Bs[cb ^ 1][w * 512]);
    }
    bf16x8 af[4], bfr[2];
#pragma unroll
    for (int i = 0; i < 4; ++i)
      af[i] = *(const bf16x8*)&As[cb][(wa * 4 + i) * 512 + quad * 128 + lm * 8];
#pragma unroll
    for (int j = 0; j < 2; ++j)
      bfr[j] = *(const bf16x8*)&Bs[cb][(wb * 2 + j) * 512 + quad * 128 + lm * 8];
#pragma unroll
    for (int mi = 0; mi < 4; ++mi)
#pragma unroll
      for (int j = 0; j < 2; ++j)
        acc[mi][j] = __builtin_amdgcn_mfma_f32_16x16x32_bf16(
            af[mi], bfr[j], acc[mi][j], 0, 0, 0);
  }

  if (z < 2) {
#pragma unroll
    for (int j = 0; j < 2; ++j) {
      const int f = n0 + (wb * 2 + j) * 16 + lm;
      const float bv = bias[f];
      const int h = f >> 6, dk = f & 63;
#pragma unroll
      for (int mi = 0; mi < 4; ++mi)
#pragma unroll
        for (int r = 0; r < 4; ++r) {
          const int m = m0 + (wa * 4 + mi) * 16 + quad * 4 + r;
          float val = acc[mi][j][r] + bv;
          if (z == 0) val *= QSCALE;
          const int b = m >> 11, tt = m & (T_SEQ - 1);
          Yz[(((size_t)(b * NH + h) << 11) + tt) * DKH + dk] = f2bf(val);
        }
    }
  } else {  // V^T [b][h][dk][t] F16
#pragma unroll
    for (int j = 0; j < 2; ++j) {
      const int f = n0 + (wb * 2 + j) * 16 + lm;
      const float bv = bias[f];
      const int h = f >> 6, dk = f & 63;
#pragma unroll
      for (int mi = 0; mi < 4; ++mi) {
        const int t = m0 + (wa * 4 + mi) * 16 + quad * 4;
        const int b = t >> 11, tt = t & (T_SEQ - 1);
        short2 a = pkh(acc[mi][j][0] + bv, acc[mi][j][1] + bv);
        short2 c = pkh(acc[mi][j][2] + bv, acc[mi][j][3] + bv);
        short4 o = {a.x, a.y, c.x, c.y};
        *(short4*)(Yz + (((size_t)(b * NH + h) * DKH + dk) << 11) + tt) = o;
      }
    }
  }
}

// ---------- out-proj GEMM: 128x64 tile, 512 thr, 512 blocks (2/CU) ----------
__global__ __launch_bounds__(512) void gemm_out(
    const short* __restrict__ A, const short* __restrict__ Bt,
    const float* __restrict__ bias, float* __restrict__ Yf) {
  __shared__ short As[2][4096];
  __shared__ short Bs[2][2048];
  const int m0 = blockIdx.x * 128, n0 = blockIdx.y * 64;
  const int tid = threadIdx.x, w = tid >> 6, lane = tid & 63;
  const int quad = lane >> 4, lm = lane & 15, wa = w & 3, wb = w >> 2;

  const short* Ag = A + (size_t)(m0 + w * 16 + lm) * DM + quad * 8;
  const short* Bg = Bt + (size_t)(n0 + (w & 3) * 16 + lm) * DM + quad * 8;

  f32x4 acc[2][2];
#pragma unroll
  for (int i = 0; i < 2; ++i)
#pragma unroll
    for (int j = 0; j < 2; ++j) acc[i][j] = (f32x4){0.f, 0.f, 0.f, 0.f};

  GLD16(Ag, &As[0][w * 512]);
  if (w < 4) GLD16(Bg, &Bs[0][w * 512]);

  for (int kt = 0; kt < DM / 32; ++kt) {
    const int cb = kt & 1;
    __syncthreads();
    if (kt + 1 < DM / 32) {
      GLD16(Ag + (kt + 1) * 32, &As[cb ^ 1][w * 512]);
      if (w < 4) GLD16(Bg + (kt + 1) * 32, &Bs[cb ^ 1][w * 512]);
    }
    bf16x8 af[2], bfr[2];
#pragma unroll
    for (int i = 0; i < 2; ++i)
      af[i] = *(const bf16x8*)&As[cb][(wa * 2 + i) * 512 + quad * 128 + lm * 8];
#pragma unroll
    for (int j = 0; j < 2; ++j)
      bfr[j] = *(const bf16x8*)&Bs[cb][(wb * 2 + j) * 512 + quad * 128 + lm * 8];
#pragma unroll
    for (int mi = 0; mi < 2; ++mi)
#pragma unroll
      for (int j = 0; j < 2; ++j)
        acc[mi][j] = __builtin_amdgcn_mfma_f32_16x16x32_bf16(
            af[mi], bfr[j], acc[mi][j], 0, 0, 0);
  }

#pragma unroll
  for (int j = 0; j < 2; ++j) {
    const int n = n0 + (wb * 2 + j) * 16 + lm;
    const float bv = bias[n];
#pragma unroll
    for (int mi = 0; mi < 2; ++mi)
#pragma unroll
      for (int r = 0; r < 4; ++r) {
        const int m = m0 + (wa * 2 + mi) * 16 + quad * 4 + r;
        Yf[(size_t)m * DM + n] = acc[mi][j][r] + bv;
      }
  }
}

// ---------- flash attention: 256 thr (4 waves), q=64/block, 64-key tiles ----------
// Qh (pre-scaled)/Kh: [bh][t][dk] bf16. Vt: [bh][dk][t] F16. mf additive mask.
// Grid 1024 blocks, LDS 32 KiB -> 4 blocks/CU: each SIMD hosts 4 waves from
// 4 DIFFERENT blocks (independent barrier domains) for latency hiding.
// Swizzle: id = bx + gx*by; bh = id&31, qt = id>>5 -> all 32 q-tiles of a head
// on one XCD (K/V L2-resident, ~2 MB/XCD). Every wave stages 2 K + 2 V GLD16
// per tile. S^T = K.Q^T; p = exp2(s+mask). PV via mfma_f32_16x16x32_f16 with
// P B-fragments built by permlane32_swap+permlane16_swap; V^T as ds_read_b128
// (conflict-free, bank pattern == K reads).
__global__ __launch_bounds__(256) void attn_kernel(
    const short* __restrict__ Qh, const short* __restrict__ Kh,
    const short* __restrict__ Vt, const float* __restrict__ mf,
    short* __restrict__ Ao) {
  __shared__ short Ks[2][4096];
  __shared__ short Vs[2][4096];
  const int id = blockIdx.x + gridDim.x * blockIdx.y;
  const int bh = id & 31, qt = id >> 5;  // qt in [0,32)
  const int b = bh >> 4, h = bh & (NH - 1);
  const int tid = threadIdx.x, w = tid >> 6, lane = tid & 63;
  const int quad = lane >> 4, lm = lane & 15;
  const size_t base = (size_t)bh * T_SEQ * DKH;
  const float* mp = mf + b * T_SEQ;
  const int q0 = qt * 64 + w * 16;

  const short* qp = Qh + base + (size_t)(q0 + lm) * DKH;
  const bf16x8 qb0 = *(const bf16x8*)(qp + quad * 8);
  const bf16x8 qb1 = *(const bf16x8*)(qp + 32 + quad * 8);

  // staging: wave w owns rows w*16..w*16+15 of both K (keys) and V^T (d)
  const short* Kg = Kh + base + (size_t)(w * 16 + lm) * DKH + quad * 8;
  const short* Vg = Vt + base + (size_t)(w * 16 + lm) * T_SEQ + quad * 8;

  f32x4 ot[4];
#pragma unroll
  for (int i = 0; i < 4; ++i) ot[i] = (f32x4){0.f, 0.f, 0.f, 0.f};
  float l_part = 0.f;

  // stage tile 0 into buffer 0
  GLD16(Kg, &Ks[0][w * 1024]);
  GLD16(Kg + 32, &Ks[0][w * 1024 + 512]);
  GLD16(Vg, &Vs[0][w * 1024]);
  GLD16(Vg + 32, &Vs[0][w * 1024 + 512]);

  for (int kt = 0; kt < T_SEQ / 64; ++kt) {
    const int cb = kt & 1;
    const int key0 = kt * 64;
    __syncthreads();
    if (kt + 1 < T_SEQ / 64) {
      const int nk = key0 + 64;
      GLD16(Kg + (size_t)nk * DKH, &Ks[cb ^ 1][w * 1024]);
      GLD16(Kg + (size_t)nk * DKH + 32, &Ks[cb ^ 1][w * 1024 + 512]);
      GLD16(Vg + nk, &Vs[cb ^ 1][w * 1024]);
      GLD16(Vg + nk + 32, &Vs[cb ^ 1][w * 1024 + 512]);
    }

    // S^T per 16-key subtile (nt in 0..3); pack P to f16; redistribute across
    // quads so each lane holds keys quad*8..quad*8+7 of each 32-key pair
    // (the 16x16x32_f16 B-fragment). For pair kp (tiles nt=2kp, 2kp+1):
    //   swap32+swap16 yields x_s=[pe.q0,pe.q2,po.q0,po.q2], y_s=[pe.q1,...]
    //   B-frag words: j0=x0, j1=x1, j2=y0, j3=y1.
    halfx8 pb32[2];
#pragma unroll
    for (int kp = 0; kp < 2; ++kp) {
      unsigned pe0, pe1, po0, po1;
#pragma unroll
      for (int hf = 0; hf < 2; ++hf) {
        const int nt = kp * 2 + hf;
        bf16x8 ka0 = *(const bf16x8*)&Ks[cb][nt * 1024 + quad * 128 + lm * 8];
        bf16x8 ka1 = *(const bf16x8*)&Ks[cb][nt * 1024 + 512 + quad * 128 + lm * 8];
        f32x4 s = (f32x4){0.f, 0.f, 0.f, 0.f};
        s = __builtin_amdgcn_mfma_f32_16x16x32_bf16(ka0, qb0, s, 0, 0, 0);
        s = __builtin_amdgcn_mfma_f32_16x16x32_bf16(ka1, qb1, s, 0, 0, 0);
        const float4 m4 = *(const float4*)(mp + key0 + nt * 16 + quad * 4);
        float p0 = fexp2(s[0] + m4.x);
        float p1 = fexp2(s[1] + m4.y);
        float p2 = fexp2(s[2] + m4.z);
        float p3 = fexp2(s[3] + m4.w);
        l_part += (p0 + p1) + (p2 + p3);
        unsigned lo = __builtin_bit_cast(unsigned, pkh(p0, p1));
        unsigned hi = __builtin_bit_cast(unsigned, pkh(p2, p3));
        if (hf == 0) { pe0 = lo; pe1 = hi; } else { po0 = lo; po1 = hi; }
      }
      unsigned x0 = pe0, y0 = po0, x1 = pe1, y1 = po1;
      swap32(x0, y0); swap16(x0, y0);  // x0 = j0, y0 = j2
      swap32(x1, y1); swap16(x1, y1);  // x1 = j1, y1 = j3
      pb32[kp] = __builtin_bit_cast(halfx8, (uintx4){x0, x1, y0, y1});
    }

    // O^T += V^T.P^T : A-frag = V^T[d=nt2*16+lm][key=kp*32+quad*8..+7]
#pragma unroll
    for (int nt2 = 0; nt2 < 4; ++nt2) {
#pragma unroll
      for (int kp = 0; kp < 2; ++kp) {
        halfx8 va =
            *(const halfx8*)&Vs[cb][nt2 * 1024 + kp * 512 + quad * 128 + lm * 8];
        ot[nt2] =
            __builtin_amdgcn_mfma_f32_16x16x32_f16(va, pb32[kp], ot[nt2], 0, 0, 0);
      }
    }
  }
  l_part += __shfl_xor(l_part, 16, 64);
  l_part += __shfl_xor(l_part, 32, 64);
  const float inv = 1.f / l_part;
  const size_t row = (size_t)(b * T_SEQ + q0 + lm) * DM + h * DKH;
#pragma unroll
  for (int nt = 0; nt < 4; ++nt) {
    short2 a = pk2(ot[nt][0] * inv, ot[nt][1] * inv);
    short2 c = pk2(ot[nt][2] * inv, ot[nt][3] * inv);
    short4 o4 = {a.x, a.y, c.x, c.y};
    *(short4*)(Ao + row + nt * 16 + quad * 4) = o4;
  }
}

extern "C" void kernel_launch(void* const* d_in, const int* in_sizes, int n_in,
                              void* d_out, int out_size, void* d_ws, size_t ws_size,
                              hipStream_t stream) {
  const float* q = (const float*)d_in[0];
  const float* k = (const float*)d_in[1];
  const float* v = (const float*)d_in[2];
  const int* mk = (const int*)d_in[3];
  const float* Wq = (const float*)d_in[4];
  const float* bq = (const float*)d_in[5];
  const float* Wk = (const float*)d_in[6];
  const float* bk = (const float*)d_in[7];
  const float* Wv = (const float*)d_in[8];
  const float* bv = (const float*)d_in[9];
  const float* Wo = (const float*)d_in[10];
  const float* bo = (const float*)d_in[11];

  const size_t XE = (size_t)M_ROWS * DM;  // 4194304
  const size_t WE = (size_t)DM * DM;      // 1048576
  short* xb = (short*)d_ws;               // 3*XE (dead after QKV gemm)
  short* Wt = xb + 3 * XE;                // 4*WE
  short* Qh = Wt + 4 * WE;                // 3*XE: Qh, Kh, Vt(f16)
  float* mf = (float*)(Qh + 3 * XE);      // 4096 floats
  short* Ao = xb;                         // alias

  prep_x<<<dim3(1024, 1, 3), 256, 0, stream>>>(q, k, v, mk, xb, mf);
  prep_w<<<dim3(16, 16, 4), 256, 0, stream>>>(Wq, Wk, Wv, Wo, Wt);
  gemm_qkv<<<dim3(M_ROWS / 128, DM / 128, 3), 512, 0, stream>>>(
      xb, Wt, bq, bk, bv, Qh);
  attn_kernel<<<dim3(T_SEQ / 64, NB * NH), 256, 0, stream>>>(
      Qh, Qh + XE, Qh + 2 * XE, mf, Ao);
  gemm_out<<<dim3(M_ROWS / 128, DM / 64), 512, 0, stream>>>(
      Ao, Wt + 3 * WE, bo, (float*)d_out);
}

// Round 3
// 254.209 us; speedup vs baseline: 1.1678x; 1.1678x over previous
//
#include <hip/hip_runtime.h>

#define T_SEQ 2048
#define DM 1024
#define NH 16
#define DKH 64
#define NB 2
#define M_ROWS (NB * T_SEQ)  // 4096
#define QSCALE 0.18033688011112042f  // 0.125 * log2(e): exp2 domain

using bf16x8 = __attribute__((ext_vector_type(8))) __bf16;
using f32x4  = __attribute__((ext_vector_type(4))) float;
using halfx4 = __attribute__((ext_vector_type(4))) __fp16;
using halfx8 = __attribute__((ext_vector_type(8))) __fp16;
using halfx2 = __attribute__((ext_vector_type(2))) __fp16;
using uintx4 = __attribute__((ext_vector_type(4))) unsigned;

__device__ __forceinline__ short f2bf(float f) {
  unsigned u = __builtin_bit_cast(unsigned, f);
  u += 0x7fffu + ((u >> 16) & 1u);
  return (short)(u >> 16);
}

#if defined(__has_builtin) && __has_builtin(__builtin_amdgcn_cvt_pk_bf16_f32)
using bf16x2 = __attribute__((ext_vector_type(2))) __bf16;
__device__ __forceinline__ short2 pk2(float a, float b) {
  bf16x2 r = __builtin_amdgcn_cvt_pk_bf16_f32(a, b);
  return __builtin_bit_cast(short2, r);
}
#else
__device__ __forceinline__ short2 pk2(float a, float b) {
  short2 r; r.x = f2bf(a); r.y = f2bf(b); return r;
}
#endif

__device__ __forceinline__ short2 pkh(float a, float b) {  // f32x2 -> f16x2 (RTZ)
  halfx2 r = __builtin_amdgcn_cvt_pkrtz(a, b);
  return __builtin_bit_cast(short2, r);
}

#if defined(__has_builtin) && __has_builtin(__builtin_amdgcn_exp2f)
__device__ __forceinline__ float fexp2(float x) { return __builtin_amdgcn_exp2f(x); }
#else
__device__ __forceinline__ float fexp2(float x) { return exp2f(x); }
#endif

// gfx950 cross-lane row swaps (for P-fragment redistribution in PV).
// swap32: a' = [a.lo32, b.lo32], b' = [a.hi32, b.hi32]
// swap16: a' = [a.r0, b.r0, a.r2, b.r2], b' = [a.r1, b.r1, a.r3, b.r3]
#if defined(__has_builtin) && __has_builtin(__builtin_amdgcn_permlane32_swap) && \
    __has_builtin(__builtin_amdgcn_permlane16_swap)
using uintx2 = __attribute__((ext_vector_type(2))) unsigned;
__device__ __forceinline__ void swap32(unsigned& a, unsigned& b) {
  uintx2 r = __builtin_amdgcn_permlane32_swap(a, b, false, false);
  a = r.x; b = r.y;
}
__device__ __forceinline__ void swap16(unsigned& a, unsigned& b) {
  uintx2 r = __builtin_amdgcn_permlane16_swap(a, b, false, false);
  a = r.x; b = r.y;
}
#else
__device__ __forceinline__ void swap32(unsigned& a, unsigned& b) {
  asm volatile("v_permlane32_swap_b32 %0, %1" : "+v"(a), "+v"(b));
}
__device__ __forceinline__ void swap16(unsigned& a, unsigned& b) {
  asm volatile("v_permlane16_swap_b32 %0, %1" : "+v"(a), "+v"(b));
}
#endif

#define GLD16(g, l)                                                            \
  __builtin_amdgcn_global_load_lds(                                            \
      (const __attribute__((address_space(1))) void*)(g),                      \
      (__attribute__((address_space(3))) void*)(l), 16, 0, 0)

// ---------- prep: fp32 -> bf16 of q,k,v; mask -> additive float ----------
__global__ __launch_bounds__(256) void prep_x(
    const float* __restrict__ q, const float* __restrict__ k,
    const float* __restrict__ v, const int* __restrict__ mask,
    short* __restrict__ dst, float* __restrict__ mf) {
  const float* s = blockIdx.z == 0 ? q : (blockIdx.z == 1 ? k : v);
  short* d = dst + (size_t)blockIdx.z * (M_ROWS * DM);
  const int n4 = M_ROWS * DM / 4;
  for (int i = blockIdx.x * 256 + threadIdx.x; i < n4; i += gridDim.x * 256) {
    float4 f = *(const float4*)(s + i * 4);
    short2 a = pk2(f.x, f.y), b = pk2(f.z, f.w);
    short4 o = {a.x, a.y, b.x, b.y};
    *(short4*)(d + i * 4) = o;
  }
  if (blockIdx.z == 0 && blockIdx.x < 4) {
    int i = (blockIdx.x * 256 + threadIdx.x) * 4;
    int4 m = *(const int4*)(mask + i);
    float4 o = {m.x ? 0.f : -1e38f, m.y ? 0.f : -1e38f,
                m.z ? 0.f : -1e38f, m.w ? 0.f : -1e38f};
    *(float4*)(mf + i) = o;
  }
}

// ---------- prep: W [k][n] fp32 -> Wt [n][k] bf16 (4 matrices) ----------
__global__ __launch_bounds__(256) void prep_w(
    const float* __restrict__ w0, const float* __restrict__ w1,
    const float* __restrict__ w2, const float* __restrict__ w3,
    short* __restrict__ dst) {
  __shared__ short T[64][72];
  const float* W = blockIdx.z == 0 ? w0 : blockIdx.z == 1 ? w1
                   : blockIdx.z == 2 ? w2 : w3;
  short* D = dst + (size_t)blockIdx.z * (DM * DM);
  const int k0 = blockIdx.x * 64, n0 = blockIdx.y * 64;
  const int r = threadIdx.x >> 2, cs = (threadIdx.x & 3) * 16;
#pragma unroll
  for (int j = 0; j < 4; ++j) {
    float4 f = *(const float4*)(W + (size_t)(k0 + r) * DM + n0 + cs + j * 4);
    short2 a = pk2(f.x, f.y), b = pk2(f.z, f.w);
    short4 o = {a.x, a.y, b.x, b.y};
    *(short4*)&T[r][cs + j * 4] = o;
  }
  __syncthreads();
  short tmp[16];
#pragma unroll
  for (int i = 0; i < 16; ++i) tmp[i] = T[cs + i][r];
  *(int4*)(D + (size_t)(n0 + r) * DM + k0 + cs) = *(const int4*)&tmp[0];
  *(int4*)(D + (size_t)(n0 + r) * DM + k0 + cs + 8) = *(const int4*)&tmp[8];
}

// ---------- QKV GEMM (r8 512-thr form, proven): Y = A @ Bt^T + bias ----------
// z<2: headsplit bf16 [b][h][t][dk] scalar coalesced (z==0 folds QSCALE);
// z==2: V^T [b][h][dk][t] in F16 (short4 over 4 consecutive t).
__global__ __launch_bounds__(512) void gemm_qkv(
    const short* __restrict__ A_, const short* __restrict__ Bt_,
    const float* __restrict__ b0, const float* __restrict__ b1,
    const float* __restrict__ b2, short* __restrict__ Y) {
  __shared__ short As[2][4096];
  __shared__ short Bs[2][4096];
  const int z = blockIdx.z;
  const short* A = A_ + (size_t)z * (M_ROWS * DM);
  const short* Bt = Bt_ + (size_t)z * (DM * DM);
  short* Yz = Y + (size_t)z * ((size_t)M_ROWS * DM);
  const float* bias = z == 0 ? b0 : (z == 1 ? b1 : b2);
  const int m0 = blockIdx.x * 128, n0 = blockIdx.y * 128;
  const int tid = threadIdx.x, w = tid >> 6, lane = tid & 63;
  const int quad = lane >> 4, lm = lane & 15, wa = w & 1, wb = w >> 1;

  const short* Ag = A + (size_t)(m0 + w * 16 + lm) * DM + quad * 8;
  const short* Bg = Bt + (size_t)(n0 + w * 16 + lm) * DM + quad * 8;

  f32x4 acc[4][2];
#pragma unroll
  for (int i = 0; i < 4; ++i)
#pragma unroll
    for (int j = 0; j < 2; ++j) acc[i][j] = (f32x4){0.f, 0.f, 0.f, 0.f};

  GLD16(Ag, &As[0][w * 512]);
  GLD16(Bg, &Bs[0][w * 512]);

  for (int kt = 0; kt < DM / 32; ++kt) {
    const int cb = kt & 1;
    __syncthreads();
    if (kt + 1 < DM / 32) {
      GLD16(Ag + (kt + 1) * 32, &As[cb ^ 1][w * 512]);
      GLD16(Bg + (kt + 1) * 32, &Bs[cb ^ 1][w * 512]);
    }
    bf16x8 af[4], bfr[2];
#pragma unroll
    for (int i = 0; i < 4; ++i)
      af[i] = *(const bf16x8*)&As[cb][(wa * 4 + i) * 512 + quad * 128 + lm * 8];
#pragma unroll
    for (int j = 0; j < 2; ++j)
      bfr[j] = *(const bf16x8*)&Bs[cb][(wb * 2 + j) * 512 + quad * 128 + lm * 8];
#pragma unroll
    for (int mi = 0; mi < 4; ++mi)
#pragma unroll
      for (int j = 0; j < 2; ++j)
        acc[mi][j] = __builtin_amdgcn_mfma_f32_16x16x32_bf16(
            af[mi], bfr[j], acc[mi][j], 0, 0, 0);
  }

  if (z < 2) {
#pragma unroll
    for (int j = 0; j < 2; ++j) {
      const int f = n0 + (wb * 2 + j) * 16 + lm;
      const float bv = bias[f];
      const int h = f >> 6, dk = f & 63;
#pragma unroll
      for (int mi = 0; mi < 4; ++mi)
#pragma unroll
        for (int r = 0; r < 4; ++r) {
          const int m = m0 + (wa * 4 + mi) * 16 + quad * 4 + r;
          float val = acc[mi][j][r] + bv;
          if (z == 0) val *= QSCALE;
          const int b = m >> 11, tt = m & (T_SEQ - 1);
          Yz[(((size_t)(b * NH + h) << 11) + tt) * DKH + dk] = f2bf(val);
        }
    }
  } else {  // V^T [b][h][dk][t] F16
#pragma unroll
    for (int j = 0; j < 2; ++j) {
      const int f = n0 + (wb * 2 + j) * 16 + lm;
      const float bv = bias[f];
      const int h = f >> 6, dk = f & 63;
#pragma unroll
      for (int mi = 0; mi < 4; ++mi) {
        const int t = m0 + (wa * 4 + mi) * 16 + quad * 4;
        const int b = t >> 11, tt = t & (T_SEQ - 1);
        short2 a = pkh(acc[mi][j][0] + bv, acc[mi][j][1] + bv);
        short2 c = pkh(acc[mi][j][2] + bv, acc[mi][j][3] + bv);
        short4 o = {a.x, a.y, c.x, c.y};
        *(short4*)(Yz + (((size_t)(b * NH + h) * DKH + dk) << 11) + tt) = o;
      }
    }
  }
}

// ---------- out-proj GEMM: 128x64 tile, 512 thr, 512 blocks (2/CU) ----------
__global__ __launch_bounds__(512) void gemm_out(
    const short* __restrict__ A, const short* __restrict__ Bt,
    const float* __restrict__ bias, float* __restrict__ Yf) {
  __shared__ short As[2][4096];
  __shared__ short Bs[2][2048];
  const int m0 = blockIdx.x * 128, n0 = blockIdx.y * 64;
  const int tid = threadIdx.x, w = tid >> 6, lane = tid & 63;
  const int quad = lane >> 4, lm = lane & 15, wa = w & 3, wb = w >> 2;

  const short* Ag = A + (size_t)(m0 + w * 16 + lm) * DM + quad * 8;
  const short* Bg = Bt + (size_t)(n0 + (w & 3) * 16 + lm) * DM + quad * 8;

  f32x4 acc[2][2];
#pragma unroll
  for (int i = 0; i < 2; ++i)
#pragma unroll
    for (int j = 0; j < 2; ++j) acc[i][j] = (f32x4){0.f, 0.f, 0.f, 0.f};

  GLD16(Ag, &As[0][w * 512]);
  if (w < 4) GLD16(Bg, &Bs[0][w * 512]);

  for (int kt = 0; kt < DM / 32; ++kt) {
    const int cb = kt & 1;
    __syncthreads();
    if (kt + 1 < DM / 32) {
      GLD16(Ag + (kt + 1) * 32, &As[cb ^ 1][w * 512]);
      if (w < 4) GLD16(Bg + (kt + 1) * 32, &Bs[cb ^ 1][w * 512]);
    }
    bf16x8 af[2], bfr[2];
#pragma unroll
    for (int i = 0; i < 2; ++i)
      af[i] = *(const bf16x8*)&As[cb][(wa * 2 + i) * 512 + quad * 128 + lm * 8];
#pragma unroll
    for (int j = 0; j < 2; ++j)
      bfr[j] = *(const bf16x8*)&Bs[cb][(wb * 2 + j) * 512 + quad * 128 + lm * 8];
#pragma unroll
    for (int mi = 0; mi < 2; ++mi)
#pragma unroll
      for (int j = 0; j < 2; ++j)
        acc[mi][j] = __builtin_amdgcn_mfma_f32_16x16x32_bf16(
            af[mi], bfr[j], acc[mi][j], 0, 0, 0);
  }

#pragma unroll
  for (int j = 0; j < 2; ++j) {
    const int n = n0 + (wb * 2 + j) * 16 + lm;
    const float bv = bias[n];
#pragma unroll
    for (int mi = 0; mi < 2; ++mi)
#pragma unroll
      for (int r = 0; r < 4; ++r) {
        const int m = m0 + (wa * 2 + mi) * 16 + quad * 4 + r;
        Yf[(size_t)m * DM + n] = acc[mi][j][r] + bv;
      }
  }
}

// ---------- flash attention: 512 thr, 32 q/wave (2 frags), 128-key tiles ----------
// Qh (pre-scaled)/Kh: [bh][t][dk] bf16. Vt: [bh][dk][t] F16. mf additive mask.
// 256 q-rows/block -> grid 256 (1 block/CU). Each K/V ds_read_b128 feeds TWO
// MFMAs (one per q-fragment): LDS-read work per unit compute halves vs R1,
// and the two fragments are independent dep chains (2x intra-wave ILP).
// Staging/LDS layout identical to the proven R1 form: waves 0-3 stage K,
// 4-7 stage V^T (4 GLD16/wave/tile), conflict-free b128 reads, 16 barriers.
// Swizzle: bh = id&31 -> all 8 q-blocks of a head on one XCD (K/V L2-res).
// S^T = K.Q^T; p = exp2(s+mask); PV via mfma_f32_16x16x32_f16 with P
// B-fragments built by permlane32_swap+permlane16_swap.
__global__ __launch_bounds__(512) void attn_kernel(
    const short* __restrict__ Qh, const short* __restrict__ Kh,
    const short* __restrict__ Vt, const float* __restrict__ mf,
    short* __restrict__ Ao) {
  __shared__ short Ks[2][8192];
  __shared__ short Vs[2][8192];
  const int id = blockIdx.x + gridDim.x * blockIdx.y;
  const int bh = id & 31, qt = id >> 5;  // qt in [0,8)
  const int b = bh >> 4, h = bh & (NH - 1);
  const int tid = threadIdx.x, w = tid >> 6, lane = tid & 63;
  const int quad = lane >> 4, lm = lane & 15;
  const size_t base = (size_t)bh * T_SEQ * DKH;
  const float* mp = mf + b * T_SEQ;
  const int q0 = qt * 256 + w * 32;  // frag A rows q0+lm, frag B rows q0+16+lm

  const short* qpA = Qh + base + (size_t)(q0 + lm) * DKH;
  const short* qpB = qpA + (size_t)16 * DKH;
  const bf16x8 qbA0 = *(const bf16x8*)(qpA + quad * 8);
  const bf16x8 qbA1 = *(const bf16x8*)(qpA + 32 + quad * 8);
  const bf16x8 qbB0 = *(const bf16x8*)(qpB + quad * 8);
  const bf16x8 qbB1 = *(const bf16x8*)(qpB + 32 + quad * 8);

  const int sw = w & 3;
  const bool isV = w >= 4;
  const short* Kg = Kh + base + (size_t)(sw * 16 + lm) * DKH + quad * 8;
  const short* Vg = Vt + base + (size_t)(sw * 16 + lm) * T_SEQ + quad * 8;

  f32x4 otA[4], otB[4];
#pragma unroll
  for (int i = 0; i < 4; ++i) {
    otA[i] = (f32x4){0.f, 0.f, 0.f, 0.f};
    otB[i] = (f32x4){0.f, 0.f, 0.f, 0.f};
  }
  float lA = 0.f, lB = 0.f;

  // stage tile 0 into buffer 0
  if (!isV) {
    GLD16(Kg, &Ks[0][sw * 1024]);
    GLD16(Kg + 32, &Ks[0][sw * 1024 + 512]);
    GLD16(Kg + (size_t)64 * DKH, &Ks[0][(sw + 4) * 1024]);
    GLD16(Kg + (size_t)64 * DKH + 32, &Ks[0][(sw + 4) * 1024 + 512]);
  } else {
    GLD16(Vg, &Vs[0][sw * 2048]);
    GLD16(Vg + 32, &Vs[0][sw * 2048 + 512]);
    GLD16(Vg + 64, &Vs[0][sw * 2048 + 1024]);
    GLD16(Vg + 96, &Vs[0][sw * 2048 + 1536]);
  }

  for (int kt = 0; kt < T_SEQ / 128; ++kt) {
    const int cb = kt & 1;
    const int key0 = kt * 128;
    __syncthreads();
    if (kt + 1 < T_SEQ / 128) {
      const int nk = key0 + 128;
      if (!isV) {
        GLD16(Kg + (size_t)nk * DKH, &Ks[cb ^ 1][sw * 1024]);
        GLD16(Kg + (size_t)nk * DKH + 32, &Ks[cb ^ 1][sw * 1024 + 512]);
        GLD16(Kg + (size_t)(nk + 64) * DKH, &Ks[cb ^ 1][(sw + 4) * 1024]);
        GLD16(Kg + (size_t)(nk + 64) * DKH + 32, &Ks[cb ^ 1][(sw + 4) * 1024 + 512]);
      } else {
        GLD16(Vg + nk, &Vs[cb ^ 1][sw * 2048]);
        GLD16(Vg + nk + 32, &Vs[cb ^ 1][sw * 2048 + 512]);
        GLD16(Vg + nk + 64, &Vs[cb ^ 1][sw * 2048 + 1024]);
        GLD16(Vg + nk + 96, &Vs[cb ^ 1][sw * 2048 + 1536]);
      }
    }

    // S^T per 16-key subtile; each ka read feeds both q-fragments.
    // Pack P to f16; permlane32_swap+permlane16_swap redistributes so each
    // lane holds keys quad*8..+7 of each 32-key pair (16x16x32_f16 B-frag).
    halfx8 pbA[4], pbB[4];
#pragma unroll
    for (int kp = 0; kp < 4; ++kp) {
      unsigned peA0, peA1, poA0, poA1;
      unsigned peB0, peB1, poB0, poB1;
#pragma unroll
      for (int hf = 0; hf < 2; ++hf) {
        const int nt = kp * 2 + hf;
        bf16x8 ka0 = *(const bf16x8*)&Ks[cb][nt * 1024 + quad * 128 + lm * 8];
        bf16x8 ka1 = *(const bf16x8*)&Ks[cb][nt * 1024 + 512 + quad * 128 + lm * 8];
        f32x4 sA = (f32x4){0.f, 0.f, 0.f, 0.f};
        sA = __builtin_amdgcn_mfma_f32_16x16x32_bf16(ka0, qbA0, sA, 0, 0, 0);
        sA = __builtin_amdgcn_mfma_f32_16x16x32_bf16(ka1, qbA1, sA, 0, 0, 0);
        f32x4 sB = (f32x4){0.f, 0.f, 0.f, 0.f};
        sB = __builtin_amdgcn_mfma_f32_16x16x32_bf16(ka0, qbB0, sB, 0, 0, 0);
        sB = __builtin_amdgcn_mfma_f32_16x16x32_bf16(ka1, qbB1, sB, 0, 0, 0);
        const float4 m4 = *(const float4*)(mp + key0 + nt * 16 + quad * 4);
        float a0 = fexp2(sA[0] + m4.x);
        float a1 = fexp2(sA[1] + m4.y);
        float a2 = fexp2(sA[2] + m4.z);
        float a3 = fexp2(sA[3] + m4.w);
        lA += (a0 + a1) + (a2 + a3);
        float b0 = fexp2(sB[0] + m4.x);
        float b1 = fexp2(sB[1] + m4.y);
        float b2 = fexp2(sB[2] + m4.z);
        float b3 = fexp2(sB[3] + m4.w);
        lB += (b0 + b1) + (b2 + b3);
        unsigned loA = __builtin_bit_cast(unsigned, pkh(a0, a1));
        unsigned hiA = __builtin_bit_cast(unsigned, pkh(a2, a3));
        unsigned loB = __builtin_bit_cast(unsigned, pkh(b0, b1));
        unsigned hiB = __builtin_bit_cast(unsigned, pkh(b2, b3));
        if (hf == 0) {
          peA0 = loA; peA1 = hiA; peB0 = loB; peB1 = hiB;
        } else {
          poA0 = loA; poA1 = hiA; poB0 = loB; poB1 = hiB;
        }
      }
      {
        unsigned x0 = peA0, y0 = poA0, x1 = peA1, y1 = poA1;
        swap32(x0, y0); swap16(x0, y0);
        swap32(x1, y1); swap16(x1, y1);
        pbA[kp] = __builtin_bit_cast(halfx8, (uintx4){x0, x1, y0, y1});
      }
      {
        unsigned x0 = peB0, y0 = poB0, x1 = peB1, y1 = poB1;
        swap32(x0, y0); swap16(x0, y0);
        swap32(x1, y1); swap16(x1, y1);
        pbB[kp] = __builtin_bit_cast(halfx8, (uintx4){x0, x1, y0, y1});
      }
    }

    // O^T += V^T.P^T : each va read feeds both fragments' MFMAs.
#pragma unroll
    for (int nt2 = 0; nt2 < 4; ++nt2) {
#pragma unroll
      for (int kp = 0; kp < 4; ++kp) {
        halfx8 va =
            *(const halfx8*)&Vs[cb][nt2 * 2048 + kp * 512 + quad * 128 + lm * 8];
        otA[nt2] =
            __builtin_amdgcn_mfma_f32_16x16x32_f16(va, pbA[kp], otA[nt2], 0, 0, 0);
        otB[nt2] =
            __builtin_amdgcn_mfma_f32_16x16x32_f16(va, pbB[kp], otB[nt2], 0, 0, 0);
      }
    }
  }
  lA += __shfl_xor(lA, 16, 64);
  lA += __shfl_xor(lA, 32, 64);
  lB += __shfl_xor(lB, 16, 64);
  lB += __shfl_xor(lB, 32, 64);
  const float invA = 1.f / lA;
  const float invB = 1.f / lB;
  const size_t rowA = (size_t)(b * T_SEQ + q0 + lm) * DM + h * DKH;
  const size_t rowB = rowA + (size_t)16 * DM;
#pragma unroll
  for (int nt = 0; nt < 4; ++nt) {
    short2 a = pk2(otA[nt][0] * invA, otA[nt][1] * invA);
    short2 c = pk2(otA[nt][2] * invA, otA[nt][3] * invA);
    short4 o4 = {a.x, a.y, c.x, c.y};
    *(short4*)(Ao + rowA + nt * 16 + quad * 4) = o4;
    short2 e = pk2(otB[nt][0] * invB, otB[nt][1] * invB);
    short2 g = pk2(otB[nt][2] * invB, otB[nt][3] * invB);
    short4 o5 = {e.x, e.y, g.x, g.y};
    *(short4*)(Ao + rowB + nt * 16 + quad * 4) = o5;
  }
}

extern "C" void kernel_launch(void* const* d_in, const int* in_sizes, int n_in,
                              void* d_out, int out_size, void* d_ws, size_t ws_size,
                              hipStream_t stream) {
  const float* q = (const float*)d_in[0];
  const float* k = (const float*)d_in[1];
  const float* v = (const float*)d_in[2];
  const int* mk = (const int*)d_in[3];
  const float* Wq = (const float*)d_in[4];
  const float* bq = (const float*)d_in[5];
  const float* Wk = (const float*)d_in[6];
  const float* bk = (const float*)d_in[7];
  const float* Wv = (const float*)d_in[8];
  const float* bv = (const float*)d_in[9];
  const float* Wo = (const float*)d_in[10];
  const float* bo = (const float*)d_in[11];

  const size_t XE = (size_t)M_ROWS * DM;  // 4194304
  const size_t WE = (size_t)DM * DM;      // 1048576
  short* xb = (short*)d_ws;               // 3*XE (dead after QKV gemm)
  short* Wt = xb + 3 * XE;                // 4*WE
  short* Qh = Wt + 4 * WE;                // 3*XE: Qh, Kh, Vt(f16)
  float* mf = (float*)(Qh + 3 * XE);      // 4096 floats
  short* Ao = xb;                         // alias

  prep_x<<<dim3(1024, 1, 3), 256, 0, stream>>>(q, k, v, mk, xb, mf);
  prep_w<<<dim3(16, 16, 4), 256, 0, stream>>>(Wq, Wk, Wv, Wo, Wt);
  gemm_qkv<<<dim3(M_ROWS / 128, DM / 128, 3), 512, 0, stream>>>(
      xb, Wt, bq, bk, bv, Qh);
  attn_kernel<<<dim3(T_SEQ / 256, NB * NH), 512, 0, stream>>>(
      Qh, Qh + XE, Qh + 2 * XE, mf, Ao);
  gemm_out<<<dim3(M_ROWS / 128, DM / 64), 512, 0, stream>>>(
      Ao, Wt + 3 * WE, bo, (float*)d_out);
}